// Round 2
// baseline (2998.915 us; speedup 1.0000x reference)
//
#include <hip/hip_runtime.h>
#include <hip/hip_bf16.h>
#include <stdint.h>

typedef unsigned short u16;
typedef __bf16 bf16x8 __attribute__((ext_vector_type(8)));
typedef float f32x4 __attribute__((ext_vector_type(4)));

#define DD 128

__device__ __forceinline__ u16 f2bf(float f) {
  uint32_t r;
  asm("v_cvt_pk_bf16_f32 %0, %1, %2" : "=v"(r) : "v"(f), "v"(f));
  return (u16)r;
}
__device__ __forceinline__ float bf2f(u16 h) {
  union { uint32_t u; float f; } v; v.u = ((uint32_t)h) << 16;
  return v.f;
}
__device__ __forceinline__ uint32_t pack2(float a, float b) {
  uint32_t r;
  asm("v_cvt_pk_bf16_f32 %0, %1, %2" : "=v"(r) : "v"(a), "v"(b));
  return r;
}
__device__ __forceinline__ float silu_(float v) {
  return v * __builtin_amdgcn_rcpf(1.0f + __expf(-v));
}
__device__ __forceinline__ f32x4 MFMA(bf16x8 a, bf16x8 b, f32x4 c) {
  return __builtin_amdgcn_mfma_f32_16x16x32_bf16(a, b, c, 0, 0, 0);
}
#define LGKM_FENCE() do { asm volatile("s_waitcnt lgkmcnt(0)" ::: "memory"); __builtin_amdgcn_sched_barrier(0); } while (0)

// ---------------------------------------------------------------------------
// Weight prep: pack f32 [K][128] matrices into bf16 MFMA B-fragment layout.
// Frag slot for (k,n): s=k>>5, i=k&7, g=(k>>3)&3, lane=(g<<4)|(n&15), f=n>>4
//   slot = ((s*8+f)*64 + lane)*8 + i
// Segments (u16 offsets): we1a 0 | we1b 16384 | we2 32768 | wc1 49152 |
//                         wn2 65536 | wn1 81920 (K=256)
// ---------------------------------------------------------------------------
__global__ __launch_bounds__(256) void kprep(
    const float* __restrict__ we1, const float* __restrict__ we2,
    const float* __restrict__ wn1, const float* __restrict__ wn2,
    const float* __restrict__ wc1, u16* __restrict__ frags) {
  const int total = 16384 * 5 + 32768;
  for (int idx = blockIdx.x * blockDim.x + threadIdx.x; idx < total;
       idx += gridDim.x * blockDim.x) {
    const float* src; int segbase;
    if (idx < 16384)      { src = we1;          segbase = 0; }
    else if (idx < 32768) { src = we1 + 16384;  segbase = 16384; }
    else if (idx < 49152) { src = we2;          segbase = 32768; }
    else if (idx < 65536) { src = wc1;          segbase = 49152; }
    else if (idx < 81920) { src = wn2;          segbase = 65536; }
    else                  { src = wn1;          segbase = 81920; }
    int local = idx - segbase;
    int k = local >> 7, n = local & 127;
    float v = src[k * 128 + n];
    int s = k >> 5, i = k & 7, g = (k >> 3) & 3;
    int lane = (g << 4) | (n & 15), f = n >> 4;
    frags[segbase + (((s * 8 + f) * 64 + lane) << 3) + i] = f2bf(v);
  }
}

// ---------------------------------------------------------------------------
// P = h @ we1[:128] + be1 ; Q = h @ we1[128:256]  (both bf16, padded rows)
// ---------------------------------------------------------------------------
__global__ __launch_bounds__(256) void kpq(
    const float* __restrict__ h, const float* __restrict__ be1,
    const u16* __restrict__ wA, const u16* __restrict__ wB,
    u16* __restrict__ Pb, u16* __restrict__ Qb, int N) {
  __shared__ u16 act[64 * 128];
  const int tid = threadIdx.x;
  const int w = tid >> 6, l = tid & 63;
  const int lm = l & 15, lh = l >> 4;
  const int base = blockIdx.x * 64;

  {
    const int q = l & 3;
    const int rowL = w * 16 + (l >> 2);
    int node = base + rowL; if (node >= N) node = N - 1;
    const float* hs = h + (size_t)node * 128 + q * 32;
    #pragma unroll
    for (int c4 = 0; c4 < 4; ++c4) {
      float4 v0 = *(const float4*)(hs + c4 * 8);
      float4 v1 = *(const float4*)(hs + c4 * 8 + 4);
      uint4 pk;
      pk.x = pack2(v0.x, v0.y); pk.y = pack2(v0.z, v0.w);
      pk.z = pack2(v1.x, v1.y); pk.w = pack2(v1.z, v1.w);
      int c = q * 4 + c4;
      *(uint4*)&act[rowL * 128 + (((c ^ (rowL & 7))) << 3)] = pk;
    }
  }
  LGKM_FENCE();
  const int rowA = w * 16 + lm, sw = rowA & 7;
  bf16x8 a[4];
  #pragma unroll
  for (int s = 0; s < 4; ++s)
    a[s] = *(const bf16x8*)&act[rowA * 128 + (((4 * s + lh) ^ sw) << 3)];
  float be1r[8];
  #pragma unroll
  for (int f = 0; f < 8; ++f) be1r[f] = be1[16 * f + lm];

  f32x4 acc[8] = {};
  #pragma unroll
  for (int s = 0; s < 4; ++s)
    #pragma unroll
    for (int f = 0; f < 8; ++f)
      acc[f] = MFMA(a[s], *(const bf16x8*)(wA + (((s * 8 + f) * 64 + l) << 3)), acc[f]);
  #pragma unroll
  for (int f = 0; f < 8; ++f)
    #pragma unroll
    for (int r = 0; r < 4; ++r) {
      int row = base + w * 16 + lh * 4 + r;
      Pb[(size_t)row * 128 + 16 * f + lm] = f2bf(acc[f][r] + be1r[f]);
    }

  f32x4 acc2[8] = {};
  #pragma unroll
  for (int s = 0; s < 4; ++s)
    #pragma unroll
    for (int f = 0; f < 8; ++f)
      acc2[f] = MFMA(a[s], *(const bf16x8*)(wB + (((s * 8 + f) * 64 + l) << 3)), acc2[f]);
  #pragma unroll
  for (int f = 0; f < 8; ++f)
    #pragma unroll
    for (int r = 0; r < 4; ++r) {
      int row = base + w * 16 + lh * 4 + r;
      Qb[(size_t)row * 128 + 16 * f + lm] = f2bf(acc2[f][r]);
    }
}

// ---------------------------------------------------------------------------
// Edge kernel: 64 edges/block, 4 independent 16-edge wave pipelines.
// Order matters: ALL atomics trail ALL compute (vmcnt is a FIFO; atomics
// issued mid-kernel stall later loads' s_waitcnt behind atomic retirement).
// t1 = silu(P[row]+Q[col]+radial*w1c) -> GEMM(we2)+silu -> m (LDS) ->
// GEMM(wc1)+silu -> dot(wc2) -> w -> coord atomics -> aggm atomics (from a2)
// ---------------------------------------------------------------------------
__global__ __launch_bounds__(256) void kedge(
    const float* __restrict__ x, const int* __restrict__ edges,
    const float* __restrict__ we1, const float* __restrict__ be2,
    const float* __restrict__ bc1, const float* __restrict__ wc2,
    const u16* __restrict__ Pb, const u16* __restrict__ Qb,
    const u16* __restrict__ we2f, const u16* __restrict__ wc1f,
    float* __restrict__ aggm, float* __restrict__ aggx,
    float* __restrict__ cnt, int E) {
  __shared__ u16 act[64 * 128];
  __shared__ float w1c[128];
  const int tid = threadIdx.x;
  if (tid < 128) w1c[tid] = we1[256 * 128 + tid];
  __syncthreads();

  const int w = tid >> 6, l = tid & 63;
  const int lm = l & 15, lh = l >> 4;
  float be2r[8], bc1r[8], wc2r[8];
  #pragma unroll
  for (int f = 0; f < 8; ++f) {
    be2r[f] = be2[16 * f + lm];
    bc1r[f] = bc1[16 * f + lm];
    wc2r[f] = wc2[16 * f + lm];
  }

  const int tb = blockIdx.x * 64 + w * 16;     // this wave's 16 edges
  int eMine = tb + lm;
  int eC = eMine < E ? eMine : E - 1;
  const int rowv = edges[eC];
  const int colv = edges[E + eC];
  float cdx = x[rowv * 3]     - x[colv * 3];
  float cdy = x[rowv * 3 + 1] - x[colv * 3 + 1];
  float cdz = x[rowv * 3 + 2] - x[colv * 3 + 2];
  float radial = cdx * cdx + cdy * cdy + cdz * cdz;

  // ---- gather + t1 ----
  {
    const int el = l >> 2, q = l & 3;
    int rG = __shfl(rowv, el), cG = __shfl(colv, el);
    float rad = __shfl(radial, el);
    const int rowL = w * 16 + el;
    const u16* Pp = Pb + (size_t)rG * 128 + q * 32;
    const u16* Qp = Qb + (size_t)cG * 128 + q * 32;
    #pragma unroll
    for (int c4 = 0; c4 < 4; ++c4) {
      uint4 pv = *(const uint4*)(Pp + c4 * 8);
      uint4 qv = *(const uint4*)(Qp + c4 * 8);
      uint32_t pw[4] = {pv.x, pv.y, pv.z, pv.w};
      uint32_t qw[4] = {qv.x, qv.y, qv.z, qv.w};
      uint32_t ow[4];
      #pragma unroll
      for (int jj = 0; jj < 4; ++jj) {
        int fb = q * 32 + c4 * 8 + jj * 2;
        float t0 = bf2f((u16)(pw[jj] & 0xffff)) + bf2f((u16)(qw[jj] & 0xffff)) + rad * w1c[fb];
        float t1 = bf2f((u16)(pw[jj] >> 16))    + bf2f((u16)(qw[jj] >> 16))    + rad * w1c[fb + 1];
        ow[jj] = pack2(silu_(t0), silu_(t1));
      }
      int c = q * 4 + c4;
      *(uint4*)&act[rowL * 128 + ((c ^ (rowL & 7)) << 3)] =
          make_uint4(ow[0], ow[1], ow[2], ow[3]);
    }
  }
  LGKM_FENCE();

  const int rowA = w * 16 + lm, sw = rowA & 7;
  bf16x8 a[4];
  #pragma unroll
  for (int s = 0; s < 4; ++s)
    a[s] = *(const bf16x8*)&act[rowA * 128 + (((4 * s + lh) ^ sw) << 3)];

  // ---- GEMM2: m = silu(t1 @ we2 + be2) ----
  f32x4 acc[8] = {};
  #pragma unroll
  for (int s = 0; s < 4; ++s)
    #pragma unroll
    for (int f = 0; f < 8; ++f)
      acc[f] = MFMA(a[s], *(const bf16x8*)(we2f + (((s * 8 + f) * 64 + l) << 3)), acc[f]);

  // m -> LDS (bf16) for GEMM3; NO atomics yet.
  #pragma unroll
  for (int f = 0; f < 8; ++f)
    #pragma unroll
    for (int r = 0; r < 4; ++r) {
      float m = silu_(acc[f][r] + be2r[f]);
      int row = w * 16 + lh * 4 + r, col = 16 * f + lm;
      act[row * 128 + (((col >> 3) ^ (row & 7)) << 3) + (col & 7)] = f2bf(m);
    }
  LGKM_FENCE();

  // ---- GEMM3: u = silu(m @ wc1 + bc1); w = u . wc2 ----
  // a2[s] holds row rowA (edge eMine), cols [(4s+lh)*8 .. +8)
  bf16x8 a2[4];
  #pragma unroll
  for (int s = 0; s < 4; ++s)
    a2[s] = *(const bf16x8*)&act[rowA * 128 + (((4 * s + lh) ^ sw) << 3)];
  f32x4 acc3[8] = {};
  #pragma unroll
  for (int s = 0; s < 4; ++s)
    #pragma unroll
    for (int f = 0; f < 8; ++f)
      acc3[f] = MFMA(a2[s], *(const bf16x8*)(wc1f + (((s * 8 + f) * 64 + l) << 3)), acc3[f]);

  float wp[4] = {0.f, 0.f, 0.f, 0.f};
  #pragma unroll
  for (int f = 0; f < 8; ++f)
    #pragma unroll
    for (int r = 0; r < 4; ++r)
      wp[r] += silu_(acc3[f][r] + bc1r[f]) * wc2r[f];
  #pragma unroll
  for (int r = 0; r < 4; ++r) {
    wp[r] += __shfl_xor(wp[r], 1);
    wp[r] += __shfl_xor(wp[r], 2);
    wp[r] += __shfl_xor(wp[r], 4);
    wp[r] += __shfl_xor(wp[r], 8);
  }
  int er[4]; bool vr[4];
  float cdxr[4], cdyr[4], cdzr[4];
  #pragma unroll
  for (int r = 0; r < 4; ++r) {
    er[r] = __shfl(rowv, lh * 4 + r);
    vr[r] = (tb + lh * 4 + r) < E;
    cdxr[r] = __shfl(cdx, lh * 4 + r);
    cdyr[r] = __shfl(cdy, lh * 4 + r);
    cdzr[r] = __shfl(cdz, lh * 4 + r);
  }

  // ---- trailing atomics: coord ----
  if (lm == 0) {
    #pragma unroll
    for (int r = 0; r < 4; ++r) {
      if (vr[r]) {
        float wv = wp[r];
        float tx = fminf(fmaxf(cdxr[r] * wv, -2.0f), 2.0f);
        float ty = fminf(fmaxf(cdyr[r] * wv, -2.0f), 2.0f);
        float tz = fminf(fmaxf(cdzr[r] * wv, -2.0f), 2.0f);
        unsafeAtomicAdd(&aggx[(size_t)er[r] * 4 + 0], tx);
        unsafeAtomicAdd(&aggx[(size_t)er[r] * 4 + 1], ty);
        unsafeAtomicAdd(&aggx[(size_t)er[r] * 4 + 2], tz);
        unsafeAtomicAdd(&cnt[er[r]], 1.0f);
      }
    }
  }

  // ---- trailing atomics: aggm, sourced from a2 fragments (own edge's m) ----
  if (eMine < E) {
    float* dst = aggm + (size_t)rowv * 128;
    #pragma unroll
    for (int s = 0; s < 4; ++s) {
      const u16* hp = (const u16*)&a2[s];
      const int cb = (4 * s + lh) * 8;
      #pragma unroll
      for (int j = 0; j < 8; ++j)
        unsafeAtomicAdd(&dst[cb + j], bf2f(hp[j]));
    }
  }
}

// ---------------------------------------------------------------------------
// Node kernel: h_out = h + silu([h|agg_m] @ wn1 + bn1) @ wn2 + bn2
//              x_out = x + agg_x / max(cnt,1)
// ---------------------------------------------------------------------------
__global__ __launch_bounds__(256) void knode(
    const float* __restrict__ h, const float* __restrict__ x,
    const float* __restrict__ aggm, const float* __restrict__ aggx,
    const float* __restrict__ cnt, const float* __restrict__ bn1,
    const float* __restrict__ bn2, const u16* __restrict__ wn1f,
    const u16* __restrict__ wn2f, float* __restrict__ out, int N) {
  __shared__ u16 act[64 * 256];
  __shared__ u16 act2[64 * 128];
  const int tid = threadIdx.x;
  const int w = tid >> 6, l = tid & 63;
  const int lm = l & 15, lh = l >> 4;
  const int base = blockIdx.x * 64;

  if (tid < 192) {                       // x_out (3 comps x 64 nodes)
    int n = base + tid / 3, c = tid - (tid / 3) * 3;
    if (n < N) {
      float ct = fmaxf(cnt[n], 1.0f);
      out[(size_t)N * 128 + (size_t)n * 3 + c] =
          x[(size_t)n * 3 + c] + aggx[(size_t)n * 4 + c] / ct;
    }
  }

  {
    const int q = l & 3;
    const int rowL = w * 16 + (l >> 2);
    int node = base + rowL; if (node >= N) node = N - 1;
    const float* src = (q < 2) ? (h + (size_t)node * 128 + q * 64)
                               : (aggm + (size_t)node * 128 + (q - 2) * 64);
    #pragma unroll
    for (int c8 = 0; c8 < 8; ++c8) {
      float4 v0 = *(const float4*)(src + c8 * 8);
      float4 v1 = *(const float4*)(src + c8 * 8 + 4);
      uint4 pk;
      pk.x = pack2(v0.x, v0.y); pk.y = pack2(v0.z, v0.w);
      pk.z = pack2(v1.x, v1.y); pk.w = pack2(v1.z, v1.w);
      int c = q * 8 + c8;
      *(uint4*)&act[rowL * 256 + ((c ^ (rowL & 7)) << 3)] = pk;
    }
  }
  LGKM_FENCE();

  const int rowA = w * 16 + lm, sw = rowA & 7;
  float bn1r[8], bn2r[8];
  #pragma unroll
  for (int f = 0; f < 8; ++f) {
    bn1r[f] = bn1[16 * f + lm];
    bn2r[f] = bn2[16 * f + lm];
  }
  bf16x8 a[8];
  #pragma unroll
  for (int s = 0; s < 8; ++s)
    a[s] = *(const bf16x8*)&act[rowA * 256 + (((4 * s + lh) ^ sw) << 3)];
  f32x4 acc[8] = {};
  #pragma unroll
  for (int s = 0; s < 8; ++s)
    #pragma unroll
    for (int f = 0; f < 8; ++f)
      acc[f] = MFMA(a[s], *(const bf16x8*)(wn1f + (((s * 8 + f) * 64 + l) << 3)), acc[f]);
  #pragma unroll
  for (int f = 0; f < 8; ++f)
    #pragma unroll
    for (int r = 0; r < 4; ++r) {
      int row = w * 16 + lh * 4 + r, col = 16 * f + lm;
      act2[row * 128 + (((col >> 3) ^ (row & 7)) << 3) + (col & 7)] =
          f2bf(silu_(acc[f][r] + bn1r[f]));
    }
  LGKM_FENCE();

  bf16x8 a2[4];
  #pragma unroll
  for (int s = 0; s < 4; ++s)
    a2[s] = *(const bf16x8*)&act2[rowA * 128 + (((4 * s + lh) ^ sw) << 3)];
  f32x4 acc2[8] = {};
  #pragma unroll
  for (int s = 0; s < 4; ++s)
    #pragma unroll
    for (int f = 0; f < 8; ++f)
      acc2[f] = MFMA(a2[s], *(const bf16x8*)(wn2f + (((s * 8 + f) * 64 + l) << 3)), acc2[f]);
  #pragma unroll
  for (int f = 0; f < 8; ++f)
    #pragma unroll
    for (int r = 0; r < 4; ++r) {
      int n2 = base + w * 16 + lh * 4 + r;
      if (n2 < N) {
        int col = 16 * f + lm;
        out[(size_t)n2 * 128 + col] =
            h[(size_t)n2 * 128 + col] + acc2[f][r] + bn2r[f];
      }
    }
}

extern "C" void kernel_launch(void* const* d_in, const int* in_sizes, int n_in,
                              void* d_out, int out_size, void* d_ws, size_t ws_size,
                              hipStream_t stream) {
  const float* h   = (const float*)d_in[0];
  const float* x   = (const float*)d_in[1];
  const int* edges = (const int*)d_in[2];
  const float* we1 = (const float*)d_in[3];
  const float* be1 = (const float*)d_in[4];
  const float* we2 = (const float*)d_in[5];
  const float* be2 = (const float*)d_in[6];
  const float* wn1 = (const float*)d_in[7];
  const float* bn1 = (const float*)d_in[8];
  const float* wn2 = (const float*)d_in[9];
  const float* bn2 = (const float*)d_in[10];
  const float* wc1 = (const float*)d_in[11];
  const float* bc1 = (const float*)d_in[12];
  const float* wc2 = (const float*)d_in[13];

  const int N = in_sizes[0] / DD;
  const int E = in_sizes[2] / 2;
  const int NT = (N + 63) & ~63;

  u16* Pb    = (u16*)d_ws;
  u16* Qb    = Pb + (size_t)NT * DD;
  u16* frags = Qb + (size_t)NT * DD;
  float* aggm = (float*)(frags + 114688);
  float* aggx = aggm + (size_t)NT * DD;
  float* cntp = aggx + (size_t)NT * 4;
  size_t need = (size_t)NT * DD * 2 * 2 + 114688 * 2 +
                (size_t)NT * (DD * 4 + 16 + 4);
  if (ws_size < need) return;

  hipMemsetAsync(aggm, 0, (size_t)NT * (DD * 4 + 16 + 4), stream);
  hipLaunchKernelGGL(kprep, dim3(64), dim3(256), 0, stream,
                     we1, we2, wn1, wn2, wc1, frags);
  hipLaunchKernelGGL(kpq, dim3(NT / 64), dim3(256), 0, stream,
                     h, be1, frags, frags + 16384, Pb, Qb, N);
  hipLaunchKernelGGL(kedge, dim3((E + 63) / 64), dim3(256), 0, stream,
                     x, edges, we1, be2, bc1, wc2, Pb, Qb,
                     frags + 32768, frags + 49152, aggm, aggx, cntp, E);
  hipLaunchKernelGGL(knode, dim3(NT / 64), dim3(256), 0, stream,
                     h, x, aggm, aggx, cntp, bn1, bn2,
                     frags + 81920, frags + 65536, (float*)d_out, N);
}

// Round 3
// 453.805 us; speedup vs baseline: 6.6084x; 6.6084x over previous
//
#include <hip/hip_runtime.h>
#include <hip/hip_bf16.h>
#include <stdint.h>

typedef unsigned short u16;
typedef __bf16 bf16x8 __attribute__((ext_vector_type(8)));
typedef float f32x4 __attribute__((ext_vector_type(4)));

#define DD 128

__device__ __forceinline__ u16 f2bf(float f) {
  uint32_t r;
  asm("v_cvt_pk_bf16_f32 %0, %1, %2" : "=v"(r) : "v"(f), "v"(f));
  return (u16)r;
}
__device__ __forceinline__ float bf2f(u16 h) {
  union { uint32_t u; float f; } v; v.u = ((uint32_t)h) << 16;
  return v.f;
}
__device__ __forceinline__ uint32_t pack2(float a, float b) {
  uint32_t r;
  asm("v_cvt_pk_bf16_f32 %0, %1, %2" : "=v"(r) : "v"(a), "v"(b));
  return r;
}
__device__ __forceinline__ float silu_(float v) {
  return v * __builtin_amdgcn_rcpf(1.0f + __expf(-v));
}
__device__ __forceinline__ f32x4 MFMA(bf16x8 a, bf16x8 b, f32x4 c) {
  return __builtin_amdgcn_mfma_f32_16x16x32_bf16(a, b, c, 0, 0, 0);
}
#define LGKM_FENCE() do { asm volatile("s_waitcnt lgkmcnt(0)" ::: "memory"); __builtin_amdgcn_sched_barrier(0); } while (0)

// ---------------------------------------------------------------------------
// Weight prep: pack f32 [K][128] matrices into bf16 MFMA B-fragment layout.
// Frag slot for (k,n): s=k>>5, i=k&7, g=(k>>3)&3, lane=(g<<4)|(n&15), f=n>>4
//   slot = ((s*8+f)*64 + lane)*8 + i
// Segments (u16 offsets): we1a 0 | we1b 16384 | we2 32768 | wc1 49152 |
//                         wn2 65536 | wn1 81920 (K=256)
// ---------------------------------------------------------------------------
__global__ __launch_bounds__(256) void kprep(
    const float* __restrict__ we1, const float* __restrict__ we2,
    const float* __restrict__ wn1, const float* __restrict__ wn2,
    const float* __restrict__ wc1, u16* __restrict__ frags) {
  const int total = 16384 * 5 + 32768;
  for (int idx = blockIdx.x * blockDim.x + threadIdx.x; idx < total;
       idx += gridDim.x * blockDim.x) {
    const float* src; int segbase;
    if (idx < 16384)      { src = we1;          segbase = 0; }
    else if (idx < 32768) { src = we1 + 16384;  segbase = 16384; }
    else if (idx < 49152) { src = we2;          segbase = 32768; }
    else if (idx < 65536) { src = wc1;          segbase = 49152; }
    else if (idx < 81920) { src = wn2;          segbase = 65536; }
    else                  { src = wn1;          segbase = 81920; }
    int local = idx - segbase;
    int k = local >> 7, n = local & 127;
    float v = src[k * 128 + n];
    int s = k >> 5, i = k & 7, g = (k >> 3) & 3;
    int lane = (g << 4) | (n & 15), f = n >> 4;
    frags[segbase + (((s * 8 + f) * 64 + lane) << 3) + i] = f2bf(v);
  }
}

// ---------------------------------------------------------------------------
// P = h @ we1[:128] + be1 ; Q = h @ we1[128:256]  (both bf16, padded rows)
// ---------------------------------------------------------------------------
__global__ __launch_bounds__(256) void kpq(
    const float* __restrict__ h, const float* __restrict__ be1,
    const u16* __restrict__ wA, const u16* __restrict__ wB,
    u16* __restrict__ Pb, u16* __restrict__ Qb, int N) {
  __shared__ u16 act[64 * 128];
  const int tid = threadIdx.x;
  const int w = tid >> 6, l = tid & 63;
  const int lm = l & 15, lh = l >> 4;
  const int base = blockIdx.x * 64;

  {
    const int q = l & 3;
    const int rowL = w * 16 + (l >> 2);
    int node = base + rowL; if (node >= N) node = N - 1;
    const float* hs = h + (size_t)node * 128 + q * 32;
    #pragma unroll
    for (int c4 = 0; c4 < 4; ++c4) {
      float4 v0 = *(const float4*)(hs + c4 * 8);
      float4 v1 = *(const float4*)(hs + c4 * 8 + 4);
      uint4 pk;
      pk.x = pack2(v0.x, v0.y); pk.y = pack2(v0.z, v0.w);
      pk.z = pack2(v1.x, v1.y); pk.w = pack2(v1.z, v1.w);
      int c = q * 4 + c4;
      *(uint4*)&act[rowL * 128 + (((c ^ (rowL & 7))) << 3)] = pk;
    }
  }
  LGKM_FENCE();
  const int rowA = w * 16 + lm, sw = rowA & 7;
  bf16x8 a[4];
  #pragma unroll
  for (int s = 0; s < 4; ++s)
    a[s] = *(const bf16x8*)&act[rowA * 128 + (((4 * s + lh) ^ sw) << 3)];
  float be1r[8];
  #pragma unroll
  for (int f = 0; f < 8; ++f) be1r[f] = be1[16 * f + lm];

  f32x4 acc[8] = {};
  #pragma unroll
  for (int s = 0; s < 4; ++s)
    #pragma unroll
    for (int f = 0; f < 8; ++f)
      acc[f] = MFMA(a[s], *(const bf16x8*)(wA + (((s * 8 + f) * 64 + l) << 3)), acc[f]);
  #pragma unroll
  for (int f = 0; f < 8; ++f)
    #pragma unroll
    for (int r = 0; r < 4; ++r) {
      int row = base + w * 16 + lh * 4 + r;
      Pb[(size_t)row * 128 + 16 * f + lm] = f2bf(acc[f][r] + be1r[f]);
    }

  f32x4 acc2[8] = {};
  #pragma unroll
  for (int s = 0; s < 4; ++s)
    #pragma unroll
    for (int f = 0; f < 8; ++f)
      acc2[f] = MFMA(a[s], *(const bf16x8*)(wB + (((s * 8 + f) * 64 + l) << 3)), acc2[f]);
  #pragma unroll
  for (int f = 0; f < 8; ++f)
    #pragma unroll
    for (int r = 0; r < 4; ++r) {
      int row = base + w * 16 + lh * 4 + r;
      Qb[(size_t)row * 128 + 16 * f + lm] = f2bf(acc2[f][r]);
    }
}

// ---------------------------------------------------------------------------
// Edge kernel: 64 edges/block, 4 independent 16-edge wave pipelines.
// Atomics trail ALL loads (vmcnt FIFO), but keep R1's coalesced pattern:
// for each (f,r) the 16 lm-lanes write 16 consecutive floats of one row
// (4x 64B segments per instruction). cnt is packed into aggx[.*4+3].
// ---------------------------------------------------------------------------
__global__ __launch_bounds__(256) void kedge(
    const float* __restrict__ x, const int* __restrict__ edges,
    const float* __restrict__ we1, const float* __restrict__ be2,
    const float* __restrict__ bc1, const float* __restrict__ wc2,
    const u16* __restrict__ Pb, const u16* __restrict__ Qb,
    const u16* __restrict__ we2f, const u16* __restrict__ wc1f,
    float* __restrict__ aggm, float* __restrict__ aggx, int E) {
  __shared__ u16 act[64 * 128];
  __shared__ float w1c[128];
  const int tid = threadIdx.x;
  if (tid < 128) w1c[tid] = we1[256 * 128 + tid];
  __syncthreads();

  const int w = tid >> 6, l = tid & 63;
  const int lm = l & 15, lh = l >> 4;
  float be2r[8], bc1r[8], wc2r[8];
  #pragma unroll
  for (int f = 0; f < 8; ++f) {
    be2r[f] = be2[16 * f + lm];
    bc1r[f] = bc1[16 * f + lm];
    wc2r[f] = wc2[16 * f + lm];
  }

  const int tb = blockIdx.x * 64 + w * 16;     // this wave's 16 edges
  int eMine = tb + lm;
  int eC = eMine < E ? eMine : E - 1;
  const int rowv = edges[eC];
  const int colv = edges[E + eC];
  float cdx = x[rowv * 3]     - x[colv * 3];
  float cdy = x[rowv * 3 + 1] - x[colv * 3 + 1];
  float cdz = x[rowv * 3 + 2] - x[colv * 3 + 2];
  float radial = cdx * cdx + cdy * cdy + cdz * cdz;

  // ---- gather + t1 ----
  {
    const int el = l >> 2, q = l & 3;
    int rG = __shfl(rowv, el), cG = __shfl(colv, el);
    float rad = __shfl(radial, el);
    const int rowL = w * 16 + el;
    const u16* Pp = Pb + (size_t)rG * 128 + q * 32;
    const u16* Qp = Qb + (size_t)cG * 128 + q * 32;
    #pragma unroll
    for (int c4 = 0; c4 < 4; ++c4) {
      uint4 pv = *(const uint4*)(Pp + c4 * 8);
      uint4 qv = *(const uint4*)(Qp + c4 * 8);
      uint32_t pw[4] = {pv.x, pv.y, pv.z, pv.w};
      uint32_t qw[4] = {qv.x, qv.y, qv.z, qv.w};
      uint32_t ow[4];
      #pragma unroll
      for (int jj = 0; jj < 4; ++jj) {
        int fb = q * 32 + c4 * 8 + jj * 2;
        float t0 = bf2f((u16)(pw[jj] & 0xffff)) + bf2f((u16)(qw[jj] & 0xffff)) + rad * w1c[fb];
        float t1 = bf2f((u16)(pw[jj] >> 16))    + bf2f((u16)(qw[jj] >> 16))    + rad * w1c[fb + 1];
        ow[jj] = pack2(silu_(t0), silu_(t1));
      }
      int c = q * 4 + c4;
      *(uint4*)&act[rowL * 128 + ((c ^ (rowL & 7)) << 3)] =
          make_uint4(ow[0], ow[1], ow[2], ow[3]);
    }
  }
  LGKM_FENCE();

  const int rowA = w * 16 + lm, sw = rowA & 7;
  bf16x8 a[4];
  #pragma unroll
  for (int s = 0; s < 4; ++s)
    a[s] = *(const bf16x8*)&act[rowA * 128 + (((4 * s + lh) ^ sw) << 3)];

  // ---- GEMM2: m = silu(t1 @ we2 + be2); acc stays LIVE until the end ----
  f32x4 acc[8] = {};
  #pragma unroll
  for (int s = 0; s < 4; ++s)
    #pragma unroll
    for (int f = 0; f < 8; ++f)
      acc[f] = MFMA(a[s], *(const bf16x8*)(we2f + (((s * 8 + f) * 64 + l) << 3)), acc[f]);

  // m -> LDS (bf16) for GEMM3; NO atomics yet.
  #pragma unroll
  for (int f = 0; f < 8; ++f)
    #pragma unroll
    for (int r = 0; r < 4; ++r) {
      float m = silu_(acc[f][r] + be2r[f]);
      int row = w * 16 + lh * 4 + r, col = 16 * f + lm;
      act[row * 128 + (((col >> 3) ^ (row & 7)) << 3) + (col & 7)] = f2bf(m);
    }
  LGKM_FENCE();

  // ---- GEMM3: u = silu(m @ wc1 + bc1); w = u . wc2 ----
  bf16x8 a2[4];
  #pragma unroll
  for (int s = 0; s < 4; ++s)
    a2[s] = *(const bf16x8*)&act[rowA * 128 + (((4 * s + lh) ^ sw) << 3)];
  f32x4 acc3[8] = {};
  #pragma unroll
  for (int s = 0; s < 4; ++s)
    #pragma unroll
    for (int f = 0; f < 8; ++f)
      acc3[f] = MFMA(a2[s], *(const bf16x8*)(wc1f + (((s * 8 + f) * 64 + l) << 3)), acc3[f]);

  float wp[4] = {0.f, 0.f, 0.f, 0.f};
  #pragma unroll
  for (int f = 0; f < 8; ++f)
    #pragma unroll
    for (int r = 0; r < 4; ++r)
      wp[r] += silu_(acc3[f][r] + bc1r[f]) * wc2r[f];
  #pragma unroll
  for (int r = 0; r < 4; ++r) {
    wp[r] += __shfl_xor(wp[r], 1);
    wp[r] += __shfl_xor(wp[r], 2);
    wp[r] += __shfl_xor(wp[r], 4);
    wp[r] += __shfl_xor(wp[r], 8);
  }
  int er[4]; bool vr[4];
  float cdxr[4], cdyr[4], cdzr[4];
  #pragma unroll
  for (int r = 0; r < 4; ++r) {
    er[r] = __shfl(rowv, lh * 4 + r);
    vr[r] = (tb + lh * 4 + r) < E;
    cdxr[r] = __shfl(cdx, lh * 4 + r);
    cdyr[r] = __shfl(cdy, lh * 4 + r);
    cdzr[r] = __shfl(cdz, lh * 4 + r);
  }

  // ---- trailing atomics: coord (+count packed at component 3) ----
  if (lm < 4) {
    #pragma unroll
    for (int r = 0; r < 4; ++r) {
      if (vr[r]) {
        float wv = wp[r];
        float v3;
        if (lm == 0)      v3 = fminf(fmaxf(cdxr[r] * wv, -2.0f), 2.0f);
        else if (lm == 1) v3 = fminf(fmaxf(cdyr[r] * wv, -2.0f), 2.0f);
        else if (lm == 2) v3 = fminf(fmaxf(cdzr[r] * wv, -2.0f), 2.0f);
        else              v3 = 1.0f;
        unsafeAtomicAdd(&aggx[(size_t)er[r] * 4 + lm], v3);
      }
    }
  }

  // ---- trailing atomics: aggm in the coalesced (f,r)-sweep pattern ----
  #pragma unroll
  for (int f = 0; f < 8; ++f)
    #pragma unroll
    for (int r = 0; r < 4; ++r) {
      if (vr[r]) {
        float m = silu_(acc[f][r] + be2r[f]);
        unsafeAtomicAdd(&aggm[(size_t)er[r] * 128 + 16 * f + lm], m);
      }
    }
}

// ---------------------------------------------------------------------------
// Node kernel: h_out = h + silu([h|agg_m] @ wn1 + bn1) @ wn2 + bn2
//              x_out = x + agg_x / max(cnt,1), cnt = aggx[.*4+3]
// ---------------------------------------------------------------------------
__global__ __launch_bounds__(256) void knode(
    const float* __restrict__ h, const float* __restrict__ x,
    const float* __restrict__ aggm, const float* __restrict__ aggx,
    const float* __restrict__ bn1, const float* __restrict__ bn2,
    const u16* __restrict__ wn1f, const u16* __restrict__ wn2f,
    float* __restrict__ out, int N) {
  __shared__ u16 act[64 * 256];
  __shared__ u16 act2[64 * 128];
  const int tid = threadIdx.x;
  const int w = tid >> 6, l = tid & 63;
  const int lm = l & 15, lh = l >> 4;
  const int base = blockIdx.x * 64;

  if (tid < 192) {                       // x_out (3 comps x 64 nodes)
    int n = base + tid / 3, c = tid - (tid / 3) * 3;
    if (n < N) {
      float ct = fmaxf(aggx[(size_t)n * 4 + 3], 1.0f);
      out[(size_t)N * 128 + (size_t)n * 3 + c] =
          x[(size_t)n * 3 + c] + aggx[(size_t)n * 4 + c] / ct;
    }
  }

  {
    const int q = l & 3;
    const int rowL = w * 16 + (l >> 2);
    int node = base + rowL; if (node >= N) node = N - 1;
    const float* src = (q < 2) ? (h + (size_t)node * 128 + q * 64)
                               : (aggm + (size_t)node * 128 + (q - 2) * 64);
    #pragma unroll
    for (int c8 = 0; c8 < 8; ++c8) {
      float4 v0 = *(const float4*)(src + c8 * 8);
      float4 v1 = *(const float4*)(src + c8 * 8 + 4);
      uint4 pk;
      pk.x = pack2(v0.x, v0.y); pk.y = pack2(v0.z, v0.w);
      pk.z = pack2(v1.x, v1.y); pk.w = pack2(v1.z, v1.w);
      int c = q * 8 + c8;
      *(uint4*)&act[rowL * 256 + ((c ^ (rowL & 7)) << 3)] = pk;
    }
  }
  LGKM_FENCE();

  const int rowA = w * 16 + lm, sw = rowA & 7;
  float bn1r[8], bn2r[8];
  #pragma unroll
  for (int f = 0; f < 8; ++f) {
    bn1r[f] = bn1[16 * f + lm];
    bn2r[f] = bn2[16 * f + lm];
  }
  bf16x8 a[8];
  #pragma unroll
  for (int s = 0; s < 8; ++s)
    a[s] = *(const bf16x8*)&act[rowA * 256 + (((4 * s + lh) ^ sw) << 3)];
  f32x4 acc[8] = {};
  #pragma unroll
  for (int s = 0; s < 8; ++s)
    #pragma unroll
    for (int f = 0; f < 8; ++f)
      acc[f] = MFMA(a[s], *(const bf16x8*)(wn1f + (((s * 8 + f) * 64 + l) << 3)), acc[f]);
  #pragma unroll
  for (int f = 0; f < 8; ++f)
    #pragma unroll
    for (int r = 0; r < 4; ++r) {
      int row = w * 16 + lh * 4 + r, col = 16 * f + lm;
      act2[row * 128 + (((col >> 3) ^ (row & 7)) << 3) + (col & 7)] =
          f2bf(silu_(acc[f][r] + bn1r[f]));
    }
  LGKM_FENCE();

  bf16x8 a2[4];
  #pragma unroll
  for (int s = 0; s < 4; ++s)
    a2[s] = *(const bf16x8*)&act2[rowA * 128 + (((4 * s + lh) ^ sw) << 3)];
  f32x4 acc2[8] = {};
  #pragma unroll
  for (int s = 0; s < 4; ++s)
    #pragma unroll
    for (int f = 0; f < 8; ++f)
      acc2[f] = MFMA(a2[s], *(const bf16x8*)(wn2f + (((s * 8 + f) * 64 + l) << 3)), acc2[f]);
  #pragma unroll
  for (int f = 0; f < 8; ++f)
    #pragma unroll
    for (int r = 0; r < 4; ++r) {
      int n2 = base + w * 16 + lh * 4 + r;
      if (n2 < N) {
        int col = 16 * f + lm;
        out[(size_t)n2 * 128 + col] =
            h[(size_t)n2 * 128 + col] + acc2[f][r] + bn2r[f];
      }
    }
}

extern "C" void kernel_launch(void* const* d_in, const int* in_sizes, int n_in,
                              void* d_out, int out_size, void* d_ws, size_t ws_size,
                              hipStream_t stream) {
  const float* h   = (const float*)d_in[0];
  const float* x   = (const float*)d_in[1];
  const int* edges = (const int*)d_in[2];
  const float* we1 = (const float*)d_in[3];
  const float* be1 = (const float*)d_in[4];
  const float* we2 = (const float*)d_in[5];
  const float* be2 = (const float*)d_in[6];
  const float* wn1 = (const float*)d_in[7];
  const float* bn1 = (const float*)d_in[8];
  const float* wn2 = (const float*)d_in[9];
  const float* bn2 = (const float*)d_in[10];
  const float* wc1 = (const float*)d_in[11];
  const float* bc1 = (const float*)d_in[12];
  const float* wc2 = (const float*)d_in[13];

  const int N = in_sizes[0] / DD;
  const int E = in_sizes[2] / 2;
  const int NT = (N + 63) & ~63;

  u16* Pb    = (u16*)d_ws;
  u16* Qb    = Pb + (size_t)NT * DD;
  u16* frags = Qb + (size_t)NT * DD;
  float* aggm = (float*)(frags + 114688);
  float* aggx = aggm + (size_t)NT * DD;
  size_t need = (size_t)NT * DD * 2 * 2 + 114688 * 2 +
                (size_t)NT * (DD * 4 + 16);
  if (ws_size < need) return;

  hipMemsetAsync(aggm, 0, (size_t)NT * (DD * 4 + 16), stream);
  hipLaunchKernelGGL(kprep, dim3(64), dim3(256), 0, stream,
                     we1, we2, wn1, wn2, wc1, frags);
  hipLaunchKernelGGL(kpq, dim3(NT / 64), dim3(256), 0, stream,
                     h, be1, frags, frags + 16384, Pb, Qb, N);
  hipLaunchKernelGGL(kedge, dim3((E + 63) / 64), dim3(256), 0, stream,
                     x, edges, we1, be2, bc1, wc2, Pb, Qb,
                     frags + 32768, frags + 49152, aggm, aggx, E);
  hipLaunchKernelGGL(knode, dim3(NT / 64), dim3(256), 0, stream,
                     h, x, aggm, aggx, bn1, bn2,
                     frags + 81920, frags + 65536, (float*)d_out, N);
}